// Round 9
// baseline (150.135 us; speedup 1.0000x reference)
//
#include <hip/hip_runtime.h>
#include <hip/hip_bf16.h>
#include <math.h>

// Problem constants (B=1)
#define SEQ    4096
#define DMODEL 1024
#define NHEADS 8
#define DH     64
#define DINNER 512      // NHEADS*DH
#define NQKV   1536     // 3*DINNER
#define WINDOW 128
#define PERSIST 4
#define EPS 1.1920929e-07f

typedef unsigned short u16;
typedef unsigned int   u32;
typedef __bf16  bf16_8 __attribute__((ext_vector_type(8)));
typedef float   f32x4  __attribute__((ext_vector_type(4)));

union BV { bf16_8 v; u16 s[8]; };

__device__ __forceinline__ float b2f(u16 u) {
    union { u32 i; float f; } v; v.i = ((u32)u) << 16; return v.f;
}
__device__ __forceinline__ u16 f2b(float f) {
    union { float f; u32 i; } v; v.f = f;
    u32 i = v.i;
    u32 r = (i + 0x7fffu + ((i >> 16) & 1u)) >> 16;   // round-to-nearest-even
    return (u16)r;
}

// async 16B global->LDS (lane i of the wave lands at ldsbase + i*16)
#define GLD16(gp, lp) __builtin_amdgcn_global_load_lds( \
    (const __attribute__((address_space(1))) void*)(gp), \
    (__attribute__((address_space(3))) void*)(lp), 16, 0, 0)

// ---------------- prep: weight transposes (fp32->bf16) + RMSNorm, one dispatch ----------------
__device__ __forceinline__ void transpose_tile(const float* __restrict__ src,
                                               u16* __restrict__ dst,
                                               int K, int N, int bn, int bk,
                                               u16 (*t)[65], int tid) {
    int r = tid >> 4, c4 = (tid & 15) * 4;
    #pragma unroll
    for (int it = 0; it < 4; it++) {
        int row = r + it * 16;
        float4 v = *(const float4*)(src + (size_t)(bk + row) * N + bn + c4);
        t[row][c4 + 0] = f2b(v.x);
        t[row][c4 + 1] = f2b(v.y);
        t[row][c4 + 2] = f2b(v.z);
        t[row][c4 + 3] = f2b(v.w);
    }
    __syncthreads();
    #pragma unroll
    for (int it = 0; it < 4; it++) {
        int n = r + it * 16;
        u16* d = dst + (size_t)(bn + n) * K + bk + c4;
        d[0] = t[c4 + 0][n];
        d[1] = t[c4 + 1][n];
        d[2] = t[c4 + 2][n];
        d[3] = t[c4 + 3][n];
    }
}

__global__ __launch_bounds__(256) void prep_kernel(const float* __restrict__ wqkv,
                                                   const float* __restrict__ wout,
                                                   const float* __restrict__ seq,
                                                   const float* __restrict__ g,
                                                   u16* __restrict__ wqkv_bt,
                                                   u16* __restrict__ wout_bt,
                                                   u16* __restrict__ x) {
    __shared__ u16 t[64][65];
    __shared__ float wsum[4];
    int b = blockIdx.x, tid = threadIdx.x;
    if (b < 384) {
        transpose_tile(wqkv, wqkv_bt, DMODEL, NQKV, (b % 24) * 64, (b / 24) * 64, t, tid);
    } else if (b < 512) {
        int bb = b - 384;
        transpose_tile(wout, wout_bt, DINNER, DMODEL, (bb % 16) * 64, (bb / 16) * 64, t, tid);
    } else {
        int row = b - 512;
        float4 v = *(const float4*)(seq + (size_t)row * DMODEL + tid * 4);
        float ss = v.x*v.x + v.y*v.y + v.z*v.z + v.w*v.w;
        #pragma unroll
        for (int o = 32; o > 0; o >>= 1) ss += __shfl_xor(ss, o);
        if ((tid & 63) == 0) wsum[tid >> 6] = ss;
        __syncthreads();
        float tot = wsum[0] + wsum[1] + wsum[2] + wsum[3];
        float rstd = rsqrtf(tot * (1.0f / DMODEL) + EPS);
        float4 gv = *(const float4*)(g + tid * 4);
        uint2 o;
        o.x = (u32)f2b(v.x * rstd * gv.x) | ((u32)f2b(v.y * rstd * gv.y) << 16);
        o.y = (u32)f2b(v.z * rstd * gv.z) | ((u32)f2b(v.w * rstd * gv.w) << 16);
        *(uint2*)(x + (size_t)row * DMODEL + tid * 4) = o;
    }
}

// ---------------- 64x128 MFMA GEMM, BK=64, 3 blocks/CU, XCD-swizzled 1-D grid ----------------
// C[M,N] = A[M,K] @ Bt[N,K]^T  (both k-contiguous bf16).
// Wave w: rows rw0=(w&1)*32 .. +32, cols cw0=(w>>1)*64 .. +64; acc[2][4].
// LDS elem(row,kc) at u16 idx (row>>3)*512 + kc*64 + (row&7)*8  (2-way banks only).
// MODE 0: scatter bf16 C into q/k/v [head][n][64] with fused RoPE on q,k.
// MODE 1: fp32 row-major write.
template <int MODE>
__global__ __launch_bounds__(256, 3) void gemm3_kernel(const u16* __restrict__ A,
                                                       const u16* __restrict__ Bt,
                                                       u16* __restrict__ C0,
                                                       u16* __restrict__ C1,
                                                       u16* __restrict__ C2,
                                                       float* __restrict__ Cf,
                                                       int nbx, int M, int N, int K) {
    __shared__ u16 As[64 * 64];    // 8 KB
    __shared__ u16 Bs[128 * 64];   // 16 KB
    int b = blockIdx.x;
    int per = gridDim.x >> 3;
    int idx = (b & 7) * per + (b >> 3);        // XCD b&7 gets contiguous tile range
    int bx = idx % nbx, by = idx / nbx;
    int tid = threadIdx.x, lane = tid & 63, wave = tid >> 6;
    int m16 = lane & 15, quad = lane >> 4;
    int rw0 = (wave & 1) * 32, cw0 = (wave >> 1) * 64;

    f32x4 acc[2][4];
    #pragma unroll
    for (int mt = 0; mt < 2; mt++)
        #pragma unroll
        for (int nt = 0; nt < 4; nt++) acc[mt][nt] = (f32x4){0.f, 0.f, 0.f, 0.f};

    int lrow = lane & 7, lkc = lane >> 3;
    const u16* Ag = A  + (size_t)(by * 64  + lrow) * K + lkc * 8;
    const u16* Bg = Bt + (size_t)(bx * 128 + lrow) * K + lkc * 8;

    for (int k0 = 0; k0 < K; k0 += 64) {
        #pragma unroll
        for (int r = 0; r < 2; r++) {          // A: 8 groups, 2 per wave
            int gg = wave * 2 + r;
            GLD16(Ag + (size_t)(gg * 8) * K + k0, As + gg * 512);
        }
        #pragma unroll
        for (int r = 0; r < 4; r++) {          // B: 16 groups, 4 per wave
            int gg = wave * 4 + r;
            GLD16(Bg + (size_t)(gg * 8) * K + k0, Bs + gg * 512);
        }
        __syncthreads();

        #pragma unroll
        for (int kk = 0; kk < 2; kk++) {
            int kc = kk * 4 + quad;
            bf16_8 afr[2], bfr[4];
            #pragma unroll
            for (int mt = 0; mt < 2; mt++) {
                int row = rw0 + mt * 16 + m16;
                afr[mt] = *(const bf16_8*)(As + (row >> 3) * 512 + kc * 64 + (row & 7) * 8);
            }
            #pragma unroll
            for (int nt = 0; nt < 4; nt++) {
                int col = cw0 + nt * 16 + m16;
                bfr[nt] = *(const bf16_8*)(Bs + (col >> 3) * 512 + kc * 64 + (col & 7) * 8);
            }
            #pragma unroll
            for (int mt = 0; mt < 2; mt++)
                #pragma unroll
                for (int nt = 0; nt < 4; nt++)
                    acc[mt][nt] = __builtin_amdgcn_mfma_f32_16x16x32_bf16(afr[mt], bfr[nt], acc[mt][nt], 0, 0, 0);
        }
        __syncthreads();
    }

    // epilogue: C/D layout row=quad*4+r, col=lane&15
    #pragma unroll
    for (int nt = 0; nt < 4; nt++) {
        int col = bx * 128 + cw0 + nt * 16 + m16;
        if (MODE == 0) {
            int tt = (col & 63) >> 1;
            float inv = exp2f(-(float)(2 * tt) * (13.287712379549449f / 64.0f));
            bool isv = (col >= 2 * DINNER);
            bool odd = (col & 1);
            int tens = col >> 9, hh = (col >> 6) & 7, dh = col & 63;
            u16* dst = (tens == 0) ? C0 : ((tens == 1) ? C1 : C2);
            #pragma unroll
            for (int mt = 0; mt < 2; mt++) {
                #pragma unroll
                for (int r = 0; r < 4; r++) {
                    int row = by * 64 + rw0 + mt * 16 + quad * 4 + r;
                    float own = acc[mt][nt][r];
                    float part = __shfl_xor(own, 1);
                    float val = own;
                    if (!isv) {
                        float s, c;
                        __sincosf((float)row * inv, &s, &c);
                        val = odd ? (own * c + part * s) : (own * c - part * s);
                    }
                    dst[((size_t)hh * SEQ + row) * DH + dh] = f2b(val);
                }
            }
        } else {
            #pragma unroll
            for (int mt = 0; mt < 2; mt++) {
                #pragma unroll
                for (int r = 0; r < 4; r++) {
                    int row = by * 64 + rw0 + mt * 16 + quad * 4 + r;
                    Cf[(size_t)row * N + col] = acc[mt][nt][r];
                }
            }
        }
    }
}

// ---------------- Attention: MFMA flash-style, Vt layout for b128 PV reads ----------------
#define AROWS 208
#define KLD   72      // Ks row stride (u16)
#define PLD   168     // Ps row stride (u16)
#define VLD   222     // Vt row stride (u16)

__global__ __launch_bounds__(256, 2) void attn_mfma(const u16* __restrict__ Q,
                                                    const u16* __restrict__ Kt,
                                                    const u16* __restrict__ V,
                                                    u16* __restrict__ O) {
    __shared__ __align__(16) char smem[29952 + 64 * VLD * 2];
    u16* Ks = (u16*)smem;                       // [208][72]
    u16* Ps = (u16*)smem;                       // [4*16][168]  (after barrier)
    u16* Vt = (u16*)(smem + 29952);             // [64][222]    d-major
    int i0 = blockIdx.x * 64, h = blockIdx.y;
    int tid = threadIdx.x, wave = tid >> 6, lane = tid & 63;
    int m16 = lane & 15, quad = lane >> 4;
    int smin = (i0 > WINDOW) ? i0 - WINDOW : 0;

    for (int idx = tid; idx < AROWS * 8; idx += 256) {
        int row = idx >> 3, c = idx & 7;
        int j = (row < 16) ? row : (smin + row - 16);
        size_t goff = ((size_t)h * SEQ + j) * DH + c * 8;
        *(bf16_8*)(Ks + row * KLD + c * 8) = *(const bf16_8*)(Kt + goff);
        union BV u; u.v = *(const bf16_8*)(V + goff);
        #pragma unroll
        for (int e = 0; e < 8; e++) Vt[(c * 8 + e) * VLD + row] = u.s[e];
    }

    int iw0 = i0 + wave * 16;
    int iq = iw0 + m16;
    const u16* qrow = Q + ((size_t)h * SEQ + iq) * DH;
    bf16_8 qa = *(const bf16_8*)(qrow + quad * 8);
    bf16_8 qb = *(const bf16_8*)(qrow + 32 + quad * 8);
    __syncthreads();

    int start_w = (iw0 > WINDOW) ? iw0 - WINDOW : 0;
    int Dw = start_w - smin;
    int tlast = 31 + iw0 - start_w;
    int nch = (tlast >> 4) + 1;                  // <=10
    int nk32 = (tlast >> 5) + 1;                 // <=5

    f32x4 S[10];
    #pragma unroll
    for (int c = 0; c < 10; c++) {
        if (c < nch) {
            int t = c * 16 + m16;
            int row = (c == 0) ? t : (t + Dw);
            const u16* kp = Ks + row * KLD;
            bf16_8 kb0 = *(const bf16_8*)(kp + quad * 8);
            bf16_8 kb1 = *(const bf16_8*)(kp + 32 + quad * 8);
            f32x4 s = (f32x4){0.f, 0.f, 0.f, 0.f};
            s = __builtin_amdgcn_mfma_f32_16x16x32_bf16(qa, kb0, s, 0, 0, 0);
            s = __builtin_amdgcn_mfma_f32_16x16x32_bf16(qb, kb1, s, 0, 0, 0);
            S[c] = s;
        }
    }
    __syncthreads();   // Ks dead after this point; Ps may now overwrite it

    float mrow[4] = {-1e30f, -1e30f, -1e30f, -1e30f};
    #pragma unroll
    for (int c = 0; c < 10; c++) {
        if (c < nch) {
            int t = c * 16 + m16;
            int j = (c == 0) ? t : (start_w + t - 16);
            #pragma unroll
            for (int r = 0; r < 4; r++) {
                int i = iw0 + quad * 4 + r;
                bool valid = (c == 0) ? (j < PERSIST && j < start_w)
                                      : (j <= i && (i - j <= WINDOW || j < PERSIST));
                float sv = valid ? S[c][r] * 0.125f : -1e30f;
                S[c][r] = sv;
                mrow[r] = fmaxf(mrow[r], sv);
            }
        }
    }
    #pragma unroll
    for (int r = 0; r < 4; r++) {
        #pragma unroll
        for (int o = 1; o < 16; o <<= 1) mrow[r] = fmaxf(mrow[r], __shfl_xor(mrow[r], o));
    }
    float srow[4] = {0.f, 0.f, 0.f, 0.f};
    #pragma unroll
    for (int c = 0; c < 10; c++) {
        if (c < nch) {
            #pragma unroll
            for (int r = 0; r < 4; r++) {
                float p = expf(S[c][r] - mrow[r]);
                S[c][r] = p;
                srow[r] += p;
            }
        }
    }
    #pragma unroll
    for (int r = 0; r < 4; r++) {
        #pragma unroll
        for (int o = 1; o < 16; o <<= 1) srow[r] += __shfl_xor(srow[r], o);
    }

    u16* pw = Ps + wave * 16 * PLD;
    #pragma unroll
    for (int c = 0; c < 10; c++) {
        #pragma unroll
        for (int r = 0; r < 4; r++) {
            u16 val = (c < nch) ? f2b(S[c][r]) : (u16)0;
            pw[(quad * 4 + r) * PLD + c * 16 + m16] = val;
        }
    }

    f32x4 oacc[4];
    #pragma unroll
    for (int nt = 0; nt < 4; nt++) oacc[nt] = (f32x4){0.f, 0.f, 0.f, 0.f};
    #pragma unroll
    for (int c2 = 0; c2 < 5; c2++) {
        if (c2 < nk32) {
            bf16_8 af = *(const bf16_8*)(pw + m16 * PLD + c2 * 32 + quad * 8);
            int kbase = c2 * 32 + quad * 8;
            int rowb = (kbase < 16) ? kbase : (kbase + Dw);
            #pragma unroll
            for (int nt = 0; nt < 4; nt++) {
                int d = nt * 16 + m16;
                bf16_8 bv = *(const bf16_8*)(Vt + d * VLD + rowb);
                oacc[nt] = __builtin_amdgcn_mfma_f32_16x16x32_bf16(af, bv, oacc[nt], 0, 0, 0);
            }
        }
    }

    #pragma unroll
    for (int nt = 0; nt < 4; nt++) {
        #pragma unroll
        for (int r = 0; r < 4; r++) {
            int i = iw0 + quad * 4 + r;
            O[(size_t)i * DINNER + h * DH + nt * 16 + m16] = f2b(oacc[nt][r] / srow[r]);
        }
    }
}

// ---------------- launch ----------------
extern "C" void kernel_launch(void* const* d_in, const int* in_sizes, int n_in,
                              void* d_out, int out_size, void* d_ws, size_t ws_size,
                              hipStream_t stream) {
    const float* seq  = (const float*)d_in[0];   // fp32 inputs
    const float* g    = (const float*)d_in[1];
    const float* wqkv = (const float*)d_in[2];
    const float* wout = (const float*)d_in[3];
    float* out = (float*)d_out;                   // fp32 output

    char* ws = (char*)d_ws;
    u16* x       = (u16*)(ws);                            // 8 MB
    u16* q       = (u16*)(ws + 8ll  * 1024 * 1024);       // 4 MB
    u16* k       = (u16*)(ws + 12ll * 1024 * 1024);       // 4 MB
    u16* v       = (u16*)(ws + 16ll * 1024 * 1024);       // 4 MB
    u16* att     = (u16*)(ws + 20ll * 1024 * 1024);       // 4 MB
    u16* wqkv_bt = (u16*)(ws + 24ll * 1024 * 1024);       // [1536][1024] bf16, 3 MB
    u16* wout_bt = (u16*)(ws + 27ll * 1024 * 1024);       // [1024][512]  bf16, 1 MB

    prep_kernel<<<4608, 256, 0, stream>>>(wqkv, wout, seq, g, wqkv_bt, wout_bt, x);

    // QKV: M=4096 N=1536 K=1024, tiles 64x128 -> 64*12 = 768 blocks (3/CU)
    gemm3_kernel<0><<<768, 256, 0, stream>>>(x, wqkv_bt, q, k, v, nullptr,
                                             NQKV / 128, SEQ, NQKV, DMODEL);

    dim3 g2(SEQ / 64, NHEADS);
    attn_mfma<<<g2, 256, 0, stream>>>(q, k, v, att);

    // out-proj: M=4096 N=1024 K=512, tiles 64x128 -> 64*8 = 512 blocks (2/CU)
    gemm3_kernel<1><<<512, 256, 0, stream>>>(att, wout_bt, nullptr, nullptr, nullptr, out,
                                             DMODEL / 128, SEQ, DMODEL, DINNER);
}

// Round 10
// 148.730 us; speedup vs baseline: 1.0095x; 1.0095x over previous
//
#include <hip/hip_runtime.h>
#include <hip/hip_bf16.h>
#include <math.h>

// Problem constants (B=1)
#define SEQ    4096
#define DMODEL 1024
#define NHEADS 8
#define DH     64
#define DINNER 512      // NHEADS*DH
#define NQKV   1536     // 3*DINNER
#define WINDOW 128
#define PERSIST 4
#define EPS 1.1920929e-07f

typedef unsigned short u16;
typedef unsigned int   u32;
typedef __bf16  bf16_8 __attribute__((ext_vector_type(8)));
typedef float   f32x4  __attribute__((ext_vector_type(4)));

union BV { bf16_8 v; u16 s[8]; };

__device__ __forceinline__ float b2f(u16 u) {
    union { u32 i; float f; } v; v.i = ((u32)u) << 16; return v.f;
}
__device__ __forceinline__ u16 f2b(float f) {
    union { float f; u32 i; } v; v.f = f;
    u32 i = v.i;
    u32 r = (i + 0x7fffu + ((i >> 16) & 1u)) >> 16;   // round-to-nearest-even
    return (u16)r;
}

// async 16B global->LDS (lane i of the wave lands at ldsbase + i*16)
#define GLD16(gp, lp) __builtin_amdgcn_global_load_lds( \
    (const __attribute__((address_space(1))) void*)(gp), \
    (__attribute__((address_space(3))) void*)(lp), 16, 0, 0)

// ---------------- prep: weight transposes (fp32->bf16) + RMSNorm, one dispatch ----------------
__device__ __forceinline__ void transpose_tile(const float* __restrict__ src,
                                               u16* __restrict__ dst,
                                               int K, int N, int bn, int bk,
                                               u16 (*t)[65], int tid) {
    int r = tid >> 4, c4 = (tid & 15) * 4;
    #pragma unroll
    for (int it = 0; it < 4; it++) {
        int row = r + it * 16;
        float4 v = *(const float4*)(src + (size_t)(bk + row) * N + bn + c4);
        t[row][c4 + 0] = f2b(v.x);
        t[row][c4 + 1] = f2b(v.y);
        t[row][c4 + 2] = f2b(v.z);
        t[row][c4 + 3] = f2b(v.w);
    }
    __syncthreads();
    #pragma unroll
    for (int it = 0; it < 4; it++) {
        int n = r + it * 16;
        u16* d = dst + (size_t)(bn + n) * K + bk + c4;
        d[0] = t[c4 + 0][n];
        d[1] = t[c4 + 1][n];
        d[2] = t[c4 + 2][n];
        d[3] = t[c4 + 3][n];
    }
}

__global__ __launch_bounds__(256) void prep_kernel(const float* __restrict__ wqkv,
                                                   const float* __restrict__ wout,
                                                   const float* __restrict__ seq,
                                                   const float* __restrict__ g,
                                                   u16* __restrict__ wqkv_bt,
                                                   u16* __restrict__ wout_bt,
                                                   u16* __restrict__ x) {
    __shared__ u16 t[64][65];
    __shared__ float wsum[4];
    int b = blockIdx.x, tid = threadIdx.x;
    if (b < 384) {
        transpose_tile(wqkv, wqkv_bt, DMODEL, NQKV, (b % 24) * 64, (b / 24) * 64, t, tid);
    } else if (b < 512) {
        int bb = b - 384;
        transpose_tile(wout, wout_bt, DINNER, DMODEL, (bb % 16) * 64, (bb / 16) * 64, t, tid);
    } else {
        int row = b - 512;
        float4 v = *(const float4*)(seq + (size_t)row * DMODEL + tid * 4);
        float ss = v.x*v.x + v.y*v.y + v.z*v.z + v.w*v.w;
        #pragma unroll
        for (int o = 32; o > 0; o >>= 1) ss += __shfl_xor(ss, o);
        if ((tid & 63) == 0) wsum[tid >> 6] = ss;
        __syncthreads();
        float tot = wsum[0] + wsum[1] + wsum[2] + wsum[3];
        float rstd = rsqrtf(tot * (1.0f / DMODEL) + EPS);
        float4 gv = *(const float4*)(g + tid * 4);
        uint2 o;
        o.x = (u32)f2b(v.x * rstd * gv.x) | ((u32)f2b(v.y * rstd * gv.y) << 16);
        o.y = (u32)f2b(v.z * rstd * gv.z) | ((u32)f2b(v.w * rstd * gv.w) << 16);
        *(uint2*)(x + (size_t)row * DMODEL + tid * 4) = o;
    }
}

// ---------------- 64x128 MFMA GEMM, BK=64, LDS DOUBLE-BUFFER prefetch pipeline ----------------
// Per iter: issue async loads for it+1 into buf^1, compute from buf, ONE barrier.
// The barrier's implicit vmcnt(0) drains loads that flew during the compute phase
// (residual wait ~ latency - compute, vs latency + compute in the serial structure).
// LDS: 2 x (8KB A + 16KB B) = 48 KB -> 3 blocks/CU. XCD-swizzled 1-D grid.
// MODE 0: scatter bf16 C into q/k/v [head][n][64] with fused RoPE on q,k.
// MODE 1: fp32 row-major write.
template <int MODE>
__global__ __launch_bounds__(256, 3) void gemm4_kernel(const u16* __restrict__ A,
                                                       const u16* __restrict__ Bt,
                                                       u16* __restrict__ C0,
                                                       u16* __restrict__ C1,
                                                       u16* __restrict__ C2,
                                                       float* __restrict__ Cf,
                                                       int nbx, int M, int N, int K) {
    __shared__ u16 As[2][64 * 64];    // 8 KB per buffer
    __shared__ u16 Bs[2][128 * 64];   // 16 KB per buffer
    int b = blockIdx.x;
    int per = gridDim.x >> 3;
    int idx = (b & 7) * per + (b >> 3);        // XCD b&7 gets contiguous tile range
    int bx = idx % nbx, by = idx / nbx;
    int tid = threadIdx.x, lane = tid & 63, wave = tid >> 6;
    int m16 = lane & 15, quad = lane >> 4;
    int rw0 = (wave & 1) * 32, cw0 = (wave >> 1) * 64;

    f32x4 acc[2][4];
    #pragma unroll
    for (int mt = 0; mt < 2; mt++)
        #pragma unroll
        for (int nt = 0; nt < 4; nt++) acc[mt][nt] = (f32x4){0.f, 0.f, 0.f, 0.f};

    int lrow = lane & 7, lkc = lane >> 3;
    const u16* Ag = A  + (size_t)(by * 64  + lrow) * K + lkc * 8;
    const u16* Bg = Bt + (size_t)(bx * 128 + lrow) * K + lkc * 8;
    int niter = K >> 6;

    // preload iter 0 into buf 0
    {
        #pragma unroll
        for (int r = 0; r < 2; r++) { int gg = wave * 2 + r; GLD16(Ag + (size_t)(gg * 8) * K, As[0] + gg * 512); }
        #pragma unroll
        for (int r = 0; r < 4; r++) { int gg = wave * 4 + r; GLD16(Bg + (size_t)(gg * 8) * K, Bs[0] + gg * 512); }
    }
    __syncthreads();

    for (int it = 0; it < niter; it++) {
        int cur = it & 1;
        if (it + 1 < niter) {
            int k0 = (it + 1) << 6;
            int nxt = cur ^ 1;
            #pragma unroll
            for (int r = 0; r < 2; r++) { int gg = wave * 2 + r; GLD16(Ag + (size_t)(gg * 8) * K + k0, As[nxt] + gg * 512); }
            #pragma unroll
            for (int r = 0; r < 4; r++) { int gg = wave * 4 + r; GLD16(Bg + (size_t)(gg * 8) * K + k0, Bs[nxt] + gg * 512); }
        }
        #pragma unroll
        for (int kk = 0; kk < 2; kk++) {
            int kc = kk * 4 + quad;
            bf16_8 afr[2], bfr[4];
            #pragma unroll
            for (int mt = 0; mt < 2; mt++) {
                int row = rw0 + mt * 16 + m16;
                afr[mt] = *(const bf16_8*)(As[cur] + (row >> 3) * 512 + kc * 64 + (row & 7) * 8);
            }
            #pragma unroll
            for (int nt = 0; nt < 4; nt++) {
                int col = cw0 + nt * 16 + m16;
                bfr[nt] = *(const bf16_8*)(Bs[cur] + (col >> 3) * 512 + kc * 64 + (col & 7) * 8);
            }
            #pragma unroll
            for (int mt = 0; mt < 2; mt++)
                #pragma unroll
                for (int nt = 0; nt < 4; nt++)
                    acc[mt][nt] = __builtin_amdgcn_mfma_f32_16x16x32_bf16(afr[mt], bfr[nt], acc[mt][nt], 0, 0, 0);
        }
        __syncthreads();   // drains this iter's prefetch (flew during compute) + guards buf reuse
    }

    // epilogue: C/D layout row=quad*4+r, col=lane&15
    #pragma unroll
    for (int nt = 0; nt < 4; nt++) {
        int col = bx * 128 + cw0 + nt * 16 + m16;
        if (MODE == 0) {
            int tt = (col & 63) >> 1;
            float inv = exp2f(-(float)(2 * tt) * (13.287712379549449f / 64.0f));
            bool isv = (col >= 2 * DINNER);
            bool odd = (col & 1);
            int tens = col >> 9, hh = (col >> 6) & 7, dh = col & 63;
            u16* dst = (tens == 0) ? C0 : ((tens == 1) ? C1 : C2);
            #pragma unroll
            for (int mt = 0; mt < 2; mt++) {
                #pragma unroll
                for (int r = 0; r < 4; r++) {
                    int row = by * 64 + rw0 + mt * 16 + quad * 4 + r;
                    float own = acc[mt][nt][r];
                    float part = __shfl_xor(own, 1);
                    float val = own;
                    if (!isv) {
                        float s, c;
                        __sincosf((float)row * inv, &s, &c);
                        val = odd ? (own * c + part * s) : (own * c - part * s);
                    }
                    dst[((size_t)hh * SEQ + row) * DH + dh] = f2b(val);
                }
            }
        } else {
            #pragma unroll
            for (int mt = 0; mt < 2; mt++) {
                #pragma unroll
                for (int r = 0; r < 4; r++) {
                    int row = by * 64 + rw0 + mt * 16 + quad * 4 + r;
                    Cf[(size_t)row * N + col] = acc[mt][nt][r];
                }
            }
        }
    }
}

// ---------------- Attention: MFMA flash-style, Vt layout for b128 PV reads ----------------
#define AROWS 208
#define KLD   72      // Ks row stride (u16)
#define PLD   168     // Ps row stride (u16)
#define VLD   222     // Vt row stride (u16)

__global__ __launch_bounds__(256, 2) void attn_mfma(const u16* __restrict__ Q,
                                                    const u16* __restrict__ Kt,
                                                    const u16* __restrict__ V,
                                                    u16* __restrict__ O) {
    __shared__ __align__(16) char smem[29952 + 64 * VLD * 2];
    u16* Ks = (u16*)smem;                       // [208][72]
    u16* Ps = (u16*)smem;                       // [4*16][168]  (after barrier)
    u16* Vt = (u16*)(smem + 29952);             // [64][222]    d-major
    int i0 = blockIdx.x * 64, h = blockIdx.y;
    int tid = threadIdx.x, wave = tid >> 6, lane = tid & 63;
    int m16 = lane & 15, quad = lane >> 4;
    int smin = (i0 > WINDOW) ? i0 - WINDOW : 0;

    for (int idx = tid; idx < AROWS * 8; idx += 256) {
        int row = idx >> 3, c = idx & 7;
        int j = (row < 16) ? row : (smin + row - 16);
        size_t goff = ((size_t)h * SEQ + j) * DH + c * 8;
        *(bf16_8*)(Ks + row * KLD + c * 8) = *(const bf16_8*)(Kt + goff);
        union BV u; u.v = *(const bf16_8*)(V + goff);
        #pragma unroll
        for (int e = 0; e < 8; e++) Vt[(c * 8 + e) * VLD + row] = u.s[e];
    }

    int iw0 = i0 + wave * 16;
    int iq = iw0 + m16;
    const u16* qrow = Q + ((size_t)h * SEQ + iq) * DH;
    bf16_8 qa = *(const bf16_8*)(qrow + quad * 8);
    bf16_8 qb = *(const bf16_8*)(qrow + 32 + quad * 8);
    __syncthreads();

    int start_w = (iw0 > WINDOW) ? iw0 - WINDOW : 0;
    int Dw = start_w - smin;
    int tlast = 31 + iw0 - start_w;
    int nch = (tlast >> 4) + 1;                  // <=10
    int nk32 = (tlast >> 5) + 1;                 // <=5

    f32x4 S[10];
    #pragma unroll
    for (int c = 0; c < 10; c++) {
        if (c < nch) {
            int t = c * 16 + m16;
            int row = (c == 0) ? t : (t + Dw);
            const u16* kp = Ks + row * KLD;
            bf16_8 kb0 = *(const bf16_8*)(kp + quad * 8);
            bf16_8 kb1 = *(const bf16_8*)(kp + 32 + quad * 8);
            f32x4 s = (f32x4){0.f, 0.f, 0.f, 0.f};
            s = __builtin_amdgcn_mfma_f32_16x16x32_bf16(qa, kb0, s, 0, 0, 0);
            s = __builtin_amdgcn_mfma_f32_16x16x32_bf16(qb, kb1, s, 0, 0, 0);
            S[c] = s;
        }
    }
    __syncthreads();   // Ks dead after this point; Ps may now overwrite it

    float mrow[4] = {-1e30f, -1e30f, -1e30f, -1e30f};
    #pragma unroll
    for (int c = 0; c < 10; c++) {
        if (c < nch) {
            int t = c * 16 + m16;
            int j = (c == 0) ? t : (start_w + t - 16);
            #pragma unroll
            for (int r = 0; r < 4; r++) {
                int i = iw0 + quad * 4 + r;
                bool valid = (c == 0) ? (j < PERSIST && j < start_w)
                                      : (j <= i && (i - j <= WINDOW || j < PERSIST));
                float sv = valid ? S[c][r] * 0.125f : -1e30f;
                S[c][r] = sv;
                mrow[r] = fmaxf(mrow[r], sv);
            }
        }
    }
    #pragma unroll
    for (int r = 0; r < 4; r++) {
        #pragma unroll
        for (int o = 1; o < 16; o <<= 1) mrow[r] = fmaxf(mrow[r], __shfl_xor(mrow[r], o));
    }
    float srow[4] = {0.f, 0.f, 0.f, 0.f};
    #pragma unroll
    for (int c = 0; c < 10; c++) {
        if (c < nch) {
            #pragma unroll
            for (int r = 0; r < 4; r++) {
                float p = expf(S[c][r] - mrow[r]);
                S[c][r] = p;
                srow[r] += p;
            }
        }
    }
    #pragma unroll
    for (int r = 0; r < 4; r++) {
        #pragma unroll
        for (int o = 1; o < 16; o <<= 1) srow[r] += __shfl_xor(srow[r], o);
    }

    u16* pw = Ps + wave * 16 * PLD;
    #pragma unroll
    for (int c = 0; c < 10; c++) {
        #pragma unroll
        for (int r = 0; r < 4; r++) {
            u16 val = (c < nch) ? f2b(S[c][r]) : (u16)0;
            pw[(quad * 4 + r) * PLD + c * 16 + m16] = val;
        }
    }

    f32x4 oacc[4];
    #pragma unroll
    for (int nt = 0; nt < 4; nt++) oacc[nt] = (f32x4){0.f, 0.f, 0.f, 0.f};
    #pragma unroll
    for (int c2 = 0; c2 < 5; c2++) {
        if (c2 < nk32) {
            bf16_8 af = *(const bf16_8*)(pw + m16 * PLD + c2 * 32 + quad * 8);
            int kbase = c2 * 32 + quad * 8;
            int rowb = (kbase < 16) ? kbase : (kbase + Dw);
            #pragma unroll
            for (int nt = 0; nt < 4; nt++) {
                int d = nt * 16 + m16;
                bf16_8 bv = *(const bf16_8*)(Vt + d * VLD + rowb);
                oacc[nt] = __builtin_amdgcn_mfma_f32_16x16x32_bf16(af, bv, oacc[nt], 0, 0, 0);
            }
        }
    }

    #pragma unroll
    for (int nt = 0; nt < 4; nt++) {
        #pragma unroll
        for (int r = 0; r < 4; r++) {
            int i = iw0 + quad * 4 + r;
            O[(size_t)i * DINNER + h * DH + nt * 16 + m16] = f2b(oacc[nt][r] / srow[r]);
        }
    }
}

// ---------------- launch ----------------
extern "C" void kernel_launch(void* const* d_in, const int* in_sizes, int n_in,
                              void* d_out, int out_size, void* d_ws, size_t ws_size,
                              hipStream_t stream) {
    const float* seq  = (const float*)d_in[0];   // fp32 inputs
    const float* g    = (const float*)d_in[1];
    const float* wqkv = (const float*)d_in[2];
    const float* wout = (const float*)d_in[3];
    float* out = (float*)d_out;                   // fp32 output

    char* ws = (char*)d_ws;
    u16* x       = (u16*)(ws);                            // 8 MB
    u16* q       = (u16*)(ws + 8ll  * 1024 * 1024);       // 4 MB
    u16* k       = (u16*)(ws + 12ll * 1024 * 1024);       // 4 MB
    u16* v       = (u16*)(ws + 16ll * 1024 * 1024);       // 4 MB
    u16* att     = (u16*)(ws + 20ll * 1024 * 1024);       // 4 MB
    u16* wqkv_bt = (u16*)(ws + 24ll * 1024 * 1024);       // [1536][1024] bf16, 3 MB
    u16* wout_bt = (u16*)(ws + 27ll * 1024 * 1024);       // [1024][512]  bf16, 1 MB

    prep_kernel<<<4608, 256, 0, stream>>>(wqkv, wout, seq, g, wqkv_bt, wout_bt, x);

    // QKV: M=4096 N=1536 K=1024, tiles 64x128 -> 64*12 = 768 blocks (3/CU)
    gemm4_kernel<0><<<768, 256, 0, stream>>>(x, wqkv_bt, q, k, v, nullptr,
                                             NQKV / 128, SEQ, NQKV, DMODEL);

    dim3 g2(SEQ / 64, NHEADS);
    attn_mfma<<<g2, 256, 0, stream>>>(q, k, v, att);

    // out-proj: M=4096 N=1024 K=512, tiles 64x128 -> 64*8 = 512 blocks (2/CU)
    gemm4_kernel<1><<<512, 256, 0, stream>>>(att, wout_bt, nullptr, nullptr, nullptr, out,
                                             DMODEL / 128, SEQ, DMODEL, DINNER);
}